// Round 19
// baseline (102.577 us; speedup 1.0000x reference)
//
#include <hip/hip_runtime.h>

#define E_DIM 69120
#define N1 60
#define H 32
#define CC 3
#define TEB 32
#define NB2 (E_DIM / TEB)   // 2160
#define SDS 36              // ds tile stride (floats); rows 16B-aligned
#define SBA 36              // chain buffer stride (rows 16B-aligned, f2-safe)
#define SBT 36              // bufT stride
#define PSZ (N1 * H)        // 1920

typedef float f2 __attribute__((ext_vector_type(2)));

__device__ __forceinline__ f2 relu_fma2(f2 a, f2 b, f2 c) {
    return __builtin_elementwise_max(__builtin_elementwise_fma(a, b, c), (f2)(0.f));
}

// kA LDS: ds[60*36]=2160f | bufA[32*36]=1152f (bufT overlay) | bufB[32*36]=1152f
//   -> 17,856 B -> 8 blocks/CU (wave cap 8 x 4 waves = 32 waves)
// kCf LDS: bufB widened to 1920f (u_l overlay) -> 20,928 B -> 7 blocks/CU

// =====================================================================
// kA31: v_bar chain + alpha partials. 256 thr: ph1-3 (eL 0..31, hg 0..7);
// ph4: wave r owns n in [16r,16r+16), half-wave picks 8; 1 h per lane.
// =====================================================================
template<bool ATOMIC>
__global__ __launch_bounds__(256, 8) void kA31(
    const float* __restrict__ d,
    const float* __restrict__ Wfvb, const float* __restrict__ bfvb,
    const float* __restrict__ Wgvb, const float* __restrict__ bgvb,
    const float* __restrict__ Wfu,  const float* __restrict__ bfu,
    float* __restrict__ outp)
{
    __shared__ __align__(16) float ds[N1 * SDS];
    __shared__ __align__(16) float bufA[32 * SBA];
    __shared__ __align__(16) float bufB[32 * SBA];
    float* bufT = bufA;
    const int tid = threadIdx.x;
    const long sE = (long)blockIdx.x * TEB;

    // ph0: stage support tile (60 rows x 8 float4)
    for (int i = tid; i < N1 * (TEB / 4); i += 256) {
        const int n = i >> 3, c = (i & 7) * 4;
        *(float4*)(ds + n * SDS + c) = *(const float4*)(d + (long)n * E_DIM + sE + c);
    }
    __syncthreads();

    const int eL = tid & 31;
    const int h0 = (tid >> 5) * 4;

    // ph1: t1 = mean_n relu(d*wf + bf); packed, dual-n; 1/N1 folded
    {
        f2 wf[2], bf[2], ta[2], tb[2];
        #pragma unroll
        for (int q = 0; q < 2; ++q) {
            wf[q] = f2{Wfvb[h0 + 2*q] * (1.f/N1), Wfvb[h0 + 2*q + 1] * (1.f/N1)};
            bf[q] = f2{bfvb[h0 + 2*q] * (1.f/N1), bfvb[h0 + 2*q + 1] * (1.f/N1)};
            ta[q] = (f2)(0.f); tb[q] = (f2)(0.f);
        }
        const float* dp = ds + eL;
        #pragma unroll 5
        for (int n = 0; n < N1; n += 2) {
            const float dv0 = dp[n * SDS];
            const float dv1 = dp[(n + 1) * SDS];
            const f2 d02 = f2{dv0, dv0}, d12 = f2{dv1, dv1};
            #pragma unroll
            for (int q = 0; q < 2; ++q) {
                ta[q] += relu_fma2(d02, wf[q], bf[q]);
                tb[q] += relu_fma2(d12, wf[q], bf[q]);
            }
        }
        #pragma unroll
        for (int q = 0; q < 2; ++q)
            *(f2*)(bufA + eL * SBA + h0 + 2*q) = ta[q] + tb[q];
    }
    __syncthreads();

    // ph2: vb = relu(t1 @ Wgvb + bgvb) -> bufB (packed)
    {
        f2 acc[2];
        #pragma unroll
        for (int q = 0; q < 2; ++q) acc[q] = f2{bgvb[h0 + 2*q], bgvb[h0 + 2*q + 1]};
        #pragma unroll
        for (int k = 0; k < H; ++k) {
            const float t = bufA[eL * SBA + k];
            const f2 t2 = f2{t, t};
            #pragma unroll
            for (int q = 0; q < 2; ++q)
                acc[q] = __builtin_elementwise_fma(t2, *(const f2*)(Wgvb + k * H + h0 + 2*q), acc[q]);
        }
        #pragma unroll
        for (int q = 0; q < 2; ++q)
            *(f2*)(bufB + eL * SBA + h0 + 2*q) = __builtin_elementwise_max(acc[q], (f2)(0.f));
    }
    __syncthreads();

    // ph3: vw = vb @ Wu_v + b_fu -> bufT (transposed; bufA dead)
    {
        f2 acc[2];
        #pragma unroll
        for (int q = 0; q < 2; ++q) acc[q] = f2{bfu[h0 + 2*q], bfu[h0 + 2*q + 1]};
        #pragma unroll
        for (int k = 0; k < H; ++k) {
            const float t = bufB[eL * SBA + k];
            const f2 t2 = f2{t, t};
            #pragma unroll
            for (int q = 0; q < 2; ++q)
                acc[q] = __builtin_elementwise_fma(t2, *(const f2*)(Wfu + k * H + h0 + 2*q), acc[q]);
        }
        #pragma unroll
        for (int q = 0; q < 2; ++q) {
            bufT[(h0 + 2*q)     * SBT + eL] = acc[q].x;
            bufT[(h0 + 2*q + 1) * SBT + eL] = acc[q].y;
        }
    }
    __syncthreads();

    // ph4: alpha partials. bn uniform per half-wave; broadcast reads.
    {
        const int hl = tid & 31;
        const int bn = ((tid >> 6) << 4) + ((tid >> 5) & 1) * 8;   // 0..56
        const int nv = (N1 - bn < 8) ? (N1 - bn) : 8;              // 8 or 4
        const float wv = Wfu[H * H + hl];
        const f2 wv2 = f2{wv, wv};
        f2 acc2[8];
        #pragma unroll
        for (int i = 0; i < 8; ++i) acc2[i] = (f2)(0.f);
        #pragma unroll 2
        for (int e4 = 0; e4 < TEB; e4 += 4) {
            const float4 w4 = *(const float4*)(bufT + hl * SBT + e4);
            const f2 wa = f2{w4.x, w4.y}, wb = f2{w4.z, w4.w};
            #pragma unroll
            for (int i = 0; i < 8; ++i) {
                if (i < nv) {
                    const float4 di = *(const float4*)(ds + (bn + i) * SDS + e4);
                    acc2[i] += relu_fma2(f2{di.x, di.y}, wv2, wa)
                             + relu_fma2(f2{di.z, di.w}, wv2, wb);
                }
            }
        }
        if (ATOMIC) {
            #pragma unroll
            for (int i = 0; i < 8; ++i)
                if (i < nv) atomicAdd(&outp[(bn + i) * H + hl], acc2[i].x + acc2[i].y);
        } else {
            float* base = outp + (long)blockIdx.x * PSZ;
            #pragma unroll
            for (int i = 0; i < 8; ++i)
                if (i < nv) base[(bn + i) * H + hl] = acc2[i].x + acc2[i].y;
        }
    }
}

// =====================================================================
// kCf31: fused v-chain + z partials. u_l overlays bufB (1920f);
// query tile staged into ds after ph1 (loads hidden under ph2).
// =====================================================================
template<bool ATOMIC>
__global__ __launch_bounds__(256, 7) void kCf31(
    const float* __restrict__ d, const float* __restrict__ d2,
    const float* __restrict__ uwb,
    const float* __restrict__ Wfvc,
    const float* __restrict__ Wgvc, const float* __restrict__ bgvc,
    const float* __restrict__ Wfz,  const float* __restrict__ bfz,
    float* __restrict__ outp)
{
    __shared__ __align__(16) float ds[N1 * SDS];
    __shared__ __align__(16) float bufA[32 * SBA];
    __shared__ __align__(16) float bufB[PSZ];       // u_l overlay; v uses [32][36]
    float* bufT = bufA;
    float* u_l  = bufB;
    const int tid = threadIdx.x;
    const long sE = (long)blockIdx.x * TEB;

    // ph0: stage support tile + uwb (pre-scaled by 1/N1)
    for (int i = tid; i < N1 * (TEB / 4); i += 256) {
        const int n = i >> 3, c = (i & 7) * 4;
        *(float4*)(ds + n * SDS + c) = *(const float4*)(d + (long)n * E_DIM + sE + c);
    }
    for (int i = tid; i < PSZ / 4; i += 256) {
        float4 u = ((const float4*)uwb)[i];
        u.x *= (1.f / N1); u.y *= (1.f / N1); u.z *= (1.f / N1); u.w *= (1.f / N1);
        ((float4*)u_l)[i] = u;
    }
    __syncthreads();

    const int eL = tid & 31;
    const int h0 = (tid >> 5) * 4;

    // ph1: m = mean_n relu(d*wvd + u); packed, dual-n
    {
        f2 wvd[2], ma[2], mb[2];
        #pragma unroll
        for (int q = 0; q < 2; ++q) {
            wvd[q] = f2{Wfvc[H * H + h0 + 2*q] * (1.f/N1), Wfvc[H * H + h0 + 2*q + 1] * (1.f/N1)};
            ma[q] = (f2)(0.f); mb[q] = (f2)(0.f);
        }
        const float* dp = ds + eL;
        #pragma unroll 5
        for (int n = 0; n < N1; n += 2) {
            const float dv0 = dp[n * SDS];
            const float dv1 = dp[(n + 1) * SDS];
            const f2 d02 = f2{dv0, dv0}, d12 = f2{dv1, dv1};
            #pragma unroll
            for (int q = 0; q < 2; ++q) {
                const f2 u0 = *(const f2*)(u_l + n * H + h0 + 2*q);        // broadcast
                const f2 u1 = *(const f2*)(u_l + (n + 1) * H + h0 + 2*q);  // broadcast
                ma[q] += relu_fma2(d02, wvd[q], u0);
                mb[q] += relu_fma2(d12, wvd[q], u1);
            }
        }
        #pragma unroll
        for (int q = 0; q < 2; ++q)
            *(f2*)(bufA + eL * SBA + h0 + 2*q) = ma[q] + mb[q];
    }
    __syncthreads();   // B1: bufA ready; ds (support) + u_l now DEAD

    // issue query-tile loads early; HBM latency hides under ph2
    float4 q0, q1;
    {
        const int n0 = tid >> 3, c0 = (tid & 7) * 4;
        q0 = *(const float4*)(d2 + (long)n0 * E_DIM + sE + c0);
        if (tid < 224) {
            const int i1 = tid + 256, n1 = i1 >> 3, c1 = (i1 & 7) * 4;
            q1 = *(const float4*)(d2 + (long)n1 * E_DIM + sE + c1);
        }
    }

    // ph2: v = relu(m @ Wgvc + bgvc) -> bufB (u_l dead)
    {
        f2 acc[2];
        #pragma unroll
        for (int q = 0; q < 2; ++q) acc[q] = f2{bgvc[h0 + 2*q], bgvc[h0 + 2*q + 1]};
        #pragma unroll
        for (int k = 0; k < H; ++k) {
            const float t = bufA[eL * SBA + k];
            const f2 t2 = f2{t, t};
            #pragma unroll
            for (int q = 0; q < 2; ++q)
                acc[q] = __builtin_elementwise_fma(t2, *(const f2*)(Wgvc + k * H + h0 + 2*q), acc[q]);
        }
        #pragma unroll
        for (int q = 0; q < 2; ++q)
            *(f2*)(bufB + eL * SBA + h0 + 2*q) = __builtin_elementwise_max(acc[q], (f2)(0.f));
    }

    // write query tile into ds (support dead since B1)
    {
        const int n0 = tid >> 3, c0 = (tid & 7) * 4;
        *(float4*)(ds + n0 * SDS + c0) = q0;
        if (tid < 224) {
            const int i1 = tid + 256, n1 = i1 >> 3, c1 = (i1 & 7) * 4;
            *(float4*)(ds + n1 * SDS + c1) = q1;
        }
    }
    __syncthreads();   // B2: bufB + query tile ready

    // ph3: vz = v @ Wz_v + b_fz -> bufT (bufA dead)
    {
        f2 acc[2];
        #pragma unroll
        for (int q = 0; q < 2; ++q) acc[q] = f2{bfz[h0 + 2*q], bfz[h0 + 2*q + 1]};
        #pragma unroll
        for (int k = 0; k < H; ++k) {
            const float t = bufB[eL * SBA + k];
            const f2 t2 = f2{t, t};
            #pragma unroll
            for (int q = 0; q < 2; ++q)
                acc[q] = __builtin_elementwise_fma(t2, *(const f2*)(Wfz + k * H + h0 + 2*q), acc[q]);
        }
        #pragma unroll
        for (int q = 0; q < 2; ++q) {
            bufT[(h0 + 2*q)     * SBT + eL] = acc[q].x;
            bufT[(h0 + 2*q + 1) * SBT + eL] = acc[q].y;
        }
    }
    __syncthreads();   // B3: bufT ready

    // ph4: z partials; query rows from LDS
    {
        const int hl = tid & 31;
        const int bn = ((tid >> 6) << 4) + ((tid >> 5) & 1) * 8;
        const int nv = (N1 - bn < 8) ? (N1 - bn) : 8;
        const float wv = Wfz[H * H + hl];
        const f2 wv2 = f2{wv, wv};
        f2 acc2[8];
        #pragma unroll
        for (int i = 0; i < 8; ++i) acc2[i] = (f2)(0.f);
        #pragma unroll 2
        for (int e4 = 0; e4 < TEB; e4 += 4) {
            const float4 w4 = *(const float4*)(bufT + hl * SBT + e4);
            const f2 wa = f2{w4.x, w4.y}, wb = f2{w4.z, w4.w};
            #pragma unroll
            for (int i = 0; i < 8; ++i) {
                if (i < nv) {
                    const float4 di = *(const float4*)(ds + (bn + i) * SDS + e4);
                    acc2[i] += relu_fma2(f2{di.x, di.y}, wv2, wa)
                             + relu_fma2(f2{di.z, di.w}, wv2, wb);
                }
            }
        }
        if (ATOMIC) {
            #pragma unroll
            for (int i = 0; i < 8; ++i)
                if (i < nv) atomicAdd(&outp[(bn + i) * H + hl], acc2[i].x + acc2[i].y);
        } else {
            float* base = outp + (long)blockIdx.x * PSZ;
            #pragma unroll
            for (int i = 0; i < 8; ++i)
                if (i < nv) base[(bn + i) * H + hl] = acc2[i].x + acc2[i].y;
        }
    }
}

// reduce part[NB2][PSZ] -> out[PSZ]; grid = PSZ/16 = 120 blocks, 512 thr
__global__ __launch_bounds__(512) void kR(
    const float* __restrict__ part, float* __restrict__ out)
{
    __shared__ float red[32][17];
    const int tid = threadIdx.x;
    const int oLoc = tid & 15, c = tid >> 4;      // 32 chunks of <=68 rows
    const int o = blockIdx.x * 16 + oLoc;
    const int b0 = c * 68;
    const int bN = (NB2 - b0 < 68) ? (NB2 - b0) : 68;
    const float* p = part + (long)b0 * PSZ + o;
    float s = 0.f;
    #pragma unroll 4
    for (int b = 0; b < bN; ++b) s += p[(long)b * PSZ];
    red[c][oLoc] = s;
    __syncthreads();
    if (tid < 16) {
        float t = 0.f;
        #pragma unroll
        for (int ci = 0; ci < 32; ++ci) t += red[ci][tid];
        out[blockIdx.x * 16 + tid] = t;
    }
}

__global__ __launch_bounds__(1024) void kB(
    const float* __restrict__ alphaAcc, const int* __restrict__ label,
    const float* __restrict__ Wfvb, const float* __restrict__ bfvb,
    const float* __restrict__ Wgvb, const float* __restrict__ bgvb,
    const float* __restrict__ Wfu,  const float* __restrict__ bfu,
    const float* __restrict__ Wgu,  const float* __restrict__ bgu,
    const float* __restrict__ Wfvc, const float* __restrict__ bfvc,
    float* __restrict__ uwb)
{
    __shared__ float up_l[N1 * H];
    __shared__ float un_l[N1 * H];
    __shared__ float cb_l[CC * H];
    __shared__ float cw_l[CC * H];
    __shared__ int   cnt[CC];
    const int tid = threadIdx.x;

    if (tid < CC) cnt[tid] = 0;
    __syncthreads();
    if (tid < N1) atomicAdd(&cnt[label[tid]], 1);
    __syncthreads();

    if (tid < CC * H) {
        const int c = tid / H, h = tid % H;
        const float nc = (float)cnt[c];
        float s = bgvb[h];
        #pragma unroll
        for (int k = 0; k < H; ++k) {
            const float t1c = (nc * fmaxf(Wfvb[k] + bfvb[k], 0.f) +
                               ((float)N1 - nc) * fmaxf(bfvb[k], 0.f)) * (1.f / N1);
            s = fmaf(t1c, Wgvb[k * H + h], s);
        }
        cb_l[tid] = fmaxf(s, 0.f);
    }
    __syncthreads();
    if (tid < CC * H) {
        const int c = tid / H, h = tid % H;
        float s = bfu[h];
        #pragma unroll
        for (int k = 0; k < H; ++k) s = fmaf(cb_l[c * H + k], Wfu[k * H + h], s);
        cw_l[tid] = s;
    }
    __syncthreads();
    for (int t = tid; t < N1 * H; t += 1024) {
        const int n = t >> 5, h = t & 31;
        const int ln = label[n];
        const float wud = Wfu[H * H + h];
        float s = 0.f;
        #pragma unroll
        for (int c = 0; c < CC; ++c)
            s += fmaxf(cw_l[c * H + h] + ((c == ln) ? wud : 0.f), 0.f);
        up_l[t] = alphaAcc[t] * (1.f / E_DIM) + s * (1.f / CC);
    }
    __syncthreads();
    for (int t = tid; t < N1 * H; t += 1024) {
        const int n = t >> 5, h = t & 31;
        float s = bgu[h];
        #pragma unroll
        for (int k = 0; k < H; ++k) s = fmaf(up_l[n * H + k], Wgu[k * H + h], s);
        un_l[t] = fmaxf(s, 0.f);
    }
    __syncthreads();
    for (int t = tid; t < N1 * H; t += 1024) {
        const int n = t >> 5, h = t & 31;
        float s = bfvc[h];
        #pragma unroll
        for (int k = 0; k < H; ++k) s = fmaf(un_l[n * H + k], Wfvc[k * H + h], s);
        uwb[t] = s;
    }
}

__global__ __launch_bounds__(1024) void kD(
    const float* __restrict__ zAcc,
    const float* __restrict__ Wgz, const float* __restrict__ bgz,
    float* __restrict__ out)
{
    __shared__ float z_l[N1 * H];
    const int tid = threadIdx.x;
    for (int t = tid; t < N1 * H; t += 1024) z_l[t] = zAcc[t] * (1.f / E_DIM);
    __syncthreads();
    for (int t = tid; t < N1 * H; t += 1024) {
        const int n = t >> 5, h = t & 31;
        float s = bgz[h];
        #pragma unroll
        for (int k = 0; k < H; ++k) s = fmaf(z_l[n * H + k], Wgz[k * H + h], s);
        out[t] = fmaxf(s, 0.f);
    }
}

extern "C" void kernel_launch(void* const* d_in, const int* in_sizes, int n_in,
                              void* d_out, int out_size, void* d_ws, size_t ws_size,
                              hipStream_t stream)
{
    const float* sup  = (const float*)d_in[0];
    const int*   lab  = (const int*)d_in[1];
    const float* qry  = (const float*)d_in[2];
    const float* Wfvb = (const float*)d_in[3];
    const float* bfvb = (const float*)d_in[4];
    const float* Wgvb = (const float*)d_in[5];
    const float* bgvb = (const float*)d_in[6];
    const float* Wfu  = (const float*)d_in[7];
    const float* bfu  = (const float*)d_in[8];
    const float* Wgu  = (const float*)d_in[9];
    const float* bgu  = (const float*)d_in[10];
    const float* Wfvc = (const float*)d_in[11];
    const float* bfvc = (const float*)d_in[12];
    const float* Wgvc = (const float*)d_in[13];
    const float* bgvc = (const float*)d_in[14];
    const float* Wfz  = (const float*)d_in[15];
    const float* bfz  = (const float*)d_in[16];
    const float* Wgz  = (const float*)d_in[17];
    const float* bgz  = (const float*)d_in[18];
    float* out = (float*)d_out;

    float* alphaAcc = (float*)d_ws;
    float* zAcc     = alphaAcc + PSZ;
    float* uwb      = zAcc + PSZ;
    float* part     = uwb + PSZ;   // shared by both passes (stream-ordered)

    const size_t needMain = (3 * (size_t)PSZ + (size_t)NB2 * PSZ) * sizeof(float);

    if (ws_size >= needMain) {
        kA31<false><<<NB2, 256, 0, stream>>>(sup, Wfvb, bfvb, Wgvb, bgvb, Wfu, bfu, part);
        kR<<<PSZ / 16, 512, 0, stream>>>(part, alphaAcc);
        kB<<<1, 1024, 0, stream>>>(alphaAcc, lab, Wfvb, bfvb, Wgvb, bgvb, Wfu, bfu,
                                   Wgu, bgu, Wfvc, bfvc, uwb);
        kCf31<false><<<NB2, 256, 0, stream>>>(sup, qry, uwb, Wfvc, Wgvc, bgvc, Wfz, bfz, part);
        kR<<<PSZ / 16, 512, 0, stream>>>(part, zAcc);
        kD<<<1, 1024, 0, stream>>>(zAcc, Wgz, bgz, out);
    } else {
        (void)hipMemsetAsync(alphaAcc, 0, 2 * PSZ * sizeof(float), stream);
        kA31<true><<<NB2, 256, 0, stream>>>(sup, Wfvb, bfvb, Wgvb, bgvb, Wfu, bfu, alphaAcc);
        kB<<<1, 1024, 0, stream>>>(alphaAcc, lab, Wfvb, bfvb, Wgvb, bgvb, Wfu, bfu,
                                   Wgu, bgu, Wfvc, bfvc, uwb);
        kCf31<true><<<NB2, 256, 0, stream>>>(sup, qry, uwb, Wfvc, Wgvc, bgvc, Wfz, bfz, zAcc);
        kD<<<1, 1024, 0, stream>>>(zAcc, Wgz, bgz, out);
    }
}

// Round 20
// 85.257 us; speedup vs baseline: 1.2032x; 1.2032x over previous
//
#include <hip/hip_runtime.h>

#define E_DIM 69120
#define N1 60
#define H 32
#define CC 3
#define TEB 64
#define NB2 (E_DIM / TEB)   // 1080
#define SDS 68              // d-tile stride (floats); rows 16B-aligned
#define SBA 34              // chain buffer stride
#define SBT 68              // bufT stride (16B-aligned rows for b128)
#define PSZ (N1 * H)        // 1920

typedef float f2 __attribute__((ext_vector_type(2)));

__device__ __forceinline__ f2 relu_fma2(f2 a, f2 b, f2 c) {
    return __builtin_elementwise_max(__builtin_elementwise_fma(a, b, c), (f2)(0.f));
}

// LDS: ds[60*68]=4080f | bufA[64*34]=2176f (bufT[32][68] overlay)
//      | bufB[64*34]=2176f (u_l overlay in kCf) -> 33,728 B -> 4 blocks/CU
// Bracketed config (r12-r19): TEB=64 beats 32 and 128; ph1 unroll 5 and
// ph4 unroll 2 beat deeper unrolls (VGPR 36 -> occupancy 42%).

// =====================================================================
// kA23: v_bar chain + alpha partials (packed fp32 math).
// =====================================================================
template<bool ATOMIC>
__global__ __launch_bounds__(512, 4) void kA23(
    const float* __restrict__ d,
    const float* __restrict__ Wfvb, const float* __restrict__ bfvb,
    const float* __restrict__ Wgvb, const float* __restrict__ bgvb,
    const float* __restrict__ Wfu,  const float* __restrict__ bfu,
    float* __restrict__ outp)
{
    __shared__ __align__(16) float ds[N1 * SDS];
    __shared__ __align__(16) float bufA[64 * SBA];
    __shared__ __align__(16) float bufB[64 * SBA];
    float* bufT = bufA;   // [32][SBT] overlay after bufA dead
    const int tid = threadIdx.x;
    const long sE = (long)blockIdx.x * TEB;

    // ph0: stage support tile
    for (int i = tid; i < N1 * (TEB / 4); i += 512) {
        const int n = i >> 4, c = (i & 15) * 4;
        *(float4*)(ds + n * SDS + c) = *(const float4*)(d + (long)n * E_DIM + sE + c);
    }
    __syncthreads();

    const int eL = tid & 63;
    const int h0 = __builtin_amdgcn_readfirstlane((tid >> 6) * 4);

    // ph1: t1 = mean_n relu(d*wf + bf); packed, dual-n; 1/N1 folded
    {
        f2 wf[2], bf[2], ta[2], tb[2];
        #pragma unroll
        for (int q = 0; q < 2; ++q) {
            wf[q] = f2{Wfvb[h0 + 2*q] * (1.f/N1), Wfvb[h0 + 2*q + 1] * (1.f/N1)};
            bf[q] = f2{bfvb[h0 + 2*q] * (1.f/N1), bfvb[h0 + 2*q + 1] * (1.f/N1)};
            ta[q] = (f2)(0.f); tb[q] = (f2)(0.f);
        }
        const float* dp = ds + eL;
        #pragma unroll 5
        for (int n = 0; n < N1; n += 2) {
            const float dv0 = dp[n * SDS];
            const float dv1 = dp[(n + 1) * SDS];
            const f2 d02 = f2{dv0, dv0}, d12 = f2{dv1, dv1};
            #pragma unroll
            for (int q = 0; q < 2; ++q) {
                ta[q] += relu_fma2(d02, wf[q], bf[q]);
                tb[q] += relu_fma2(d12, wf[q], bf[q]);
            }
        }
        #pragma unroll
        for (int q = 0; q < 2; ++q)
            *(f2*)(bufA + eL * SBA + h0 + 2*q) = ta[q] + tb[q];
    }
    __syncthreads();

    // ph2: vb = relu(t1 @ Wgvb + bgvb) -> bufB (packed)
    {
        f2 acc[2];
        #pragma unroll
        for (int q = 0; q < 2; ++q) acc[q] = f2{bgvb[h0 + 2*q], bgvb[h0 + 2*q + 1]};
        #pragma unroll
        for (int k = 0; k < H; ++k) {
            const float t = bufA[eL * SBA + k];
            const f2 t2 = f2{t, t};
            #pragma unroll
            for (int q = 0; q < 2; ++q)
                acc[q] = __builtin_elementwise_fma(t2, *(const f2*)(Wgvb + k * H + h0 + 2*q), acc[q]);
        }
        #pragma unroll
        for (int q = 0; q < 2; ++q)
            *(f2*)(bufB + eL * SBA + h0 + 2*q) = __builtin_elementwise_max(acc[q], (f2)(0.f));
    }
    __syncthreads();

    // ph3: vw = vb @ Wu_v + b_fu -> bufT (transposed; bufA dead)
    {
        f2 acc[2];
        #pragma unroll
        for (int q = 0; q < 2; ++q) acc[q] = f2{bfu[h0 + 2*q], bfu[h0 + 2*q + 1]};
        #pragma unroll
        for (int k = 0; k < H; ++k) {
            const float t = bufB[eL * SBA + k];
            const f2 t2 = f2{t, t};
            #pragma unroll
            for (int q = 0; q < 2; ++q)
                acc[q] = __builtin_elementwise_fma(t2, *(const f2*)(Wfu + k * H + h0 + 2*q), acc[q]);
        }
        #pragma unroll
        for (int q = 0; q < 2; ++q) {
            bufT[(h0 + 2*q)     * SBT + eL] = acc[q].x;
            bufT[(h0 + 2*q + 1) * SBT + eL] = acc[q].y;
        }
    }
    __syncthreads();

    // ph4: alpha partials. wave r: n in [8r,8r+8); lane: nq2 (4 n's), hl (1 h).
    {
        const int hl = tid & 31;
        const int bn = ((tid >> 6) << 3) + ((tid >> 5) & 1) * 4;
        if (bn < N1) {
            const float wv = Wfu[H * H + hl];
            const f2 wv2 = f2{wv, wv};
            f2 acc2[4];
            #pragma unroll
            for (int i = 0; i < 4; ++i) acc2[i] = (f2)(0.f);
            const float* dr = ds + bn * SDS;
            #pragma unroll 2
            for (int e4 = 0; e4 < TEB; e4 += 4) {
                const float4 w4 = *(const float4*)(bufT + hl * SBT + e4);
                const f2 wa = f2{w4.x, w4.y}, wb = f2{w4.z, w4.w};
                #pragma unroll
                for (int i = 0; i < 4; ++i) {
                    const float4 di = *(const float4*)(dr + i * SDS + e4);
                    acc2[i] += relu_fma2(f2{di.x, di.y}, wv2, wa)
                             + relu_fma2(f2{di.z, di.w}, wv2, wb);
                }
            }
            if (ATOMIC) {
                #pragma unroll
                for (int i = 0; i < 4; ++i) atomicAdd(&outp[(bn + i) * H + hl], acc2[i].x + acc2[i].y);
            } else {
                float* base = outp + (long)blockIdx.x * PSZ;
                #pragma unroll
                for (int i = 0; i < 4; ++i) base[(bn + i) * H + hl] = acc2[i].x + acc2[i].y;
            }
        }
    }
}

// =====================================================================
// kCf23: fused v-chain + z partials (packed). Query tile staged into
// ds (dead after ph1); loads issued after B1, hidden under ph2.
// =====================================================================
template<bool ATOMIC>
__global__ __launch_bounds__(512, 4) void kCf23(
    const float* __restrict__ d, const float* __restrict__ d2,
    const float* __restrict__ uwb,
    const float* __restrict__ Wfvc,
    const float* __restrict__ Wgvc, const float* __restrict__ bgvc,
    const float* __restrict__ Wfz,  const float* __restrict__ bfz,
    float* __restrict__ outp)
{
    __shared__ __align__(16) float ds[N1 * SDS];
    __shared__ __align__(16) float bufA[64 * SBA];
    __shared__ __align__(16) float bufB[64 * SBA];
    float* bufT = bufA;
    float* u_l  = bufB;   // [60][32] overlay: read in ph1, dead before ph2 writes
    const int tid = threadIdx.x;
    const long sE = (long)blockIdx.x * TEB;

    // ph0: stage support tile + uwb (pre-scaled by 1/N1)
    for (int i = tid; i < N1 * (TEB / 4); i += 512) {
        const int n = i >> 4, c = (i & 15) * 4;
        *(float4*)(ds + n * SDS + c) = *(const float4*)(d + (long)n * E_DIM + sE + c);
    }
    if (tid < PSZ / 4) {
        float4 u = ((const float4*)uwb)[tid];
        u.x *= (1.f / N1); u.y *= (1.f / N1); u.z *= (1.f / N1); u.w *= (1.f / N1);
        ((float4*)u_l)[tid] = u;
    }
    __syncthreads();

    const int eL = tid & 63;
    const int h0 = __builtin_amdgcn_readfirstlane((tid >> 6) * 4);

    // ph1: m = mean_n relu(d*wvd + u); packed, dual-n
    {
        f2 wvd[2], ma[2], mb[2];
        #pragma unroll
        for (int q = 0; q < 2; ++q) {
            wvd[q] = f2{Wfvc[H * H + h0 + 2*q] * (1.f/N1), Wfvc[H * H + h0 + 2*q + 1] * (1.f/N1)};
            ma[q] = (f2)(0.f); mb[q] = (f2)(0.f);
        }
        const float* dp = ds + eL;
        #pragma unroll 5
        for (int n = 0; n < N1; n += 2) {
            const float dv0 = dp[n * SDS];
            const float dv1 = dp[(n + 1) * SDS];
            const f2 d02 = f2{dv0, dv0}, d12 = f2{dv1, dv1};
            #pragma unroll
            for (int q = 0; q < 2; ++q) {
                const f2 u0 = *(const f2*)(u_l + n * H + h0 + 2*q);        // broadcast
                const f2 u1 = *(const f2*)(u_l + (n + 1) * H + h0 + 2*q);  // broadcast
                ma[q] += relu_fma2(d02, wvd[q], u0);
                mb[q] += relu_fma2(d12, wvd[q], u1);
            }
        }
        #pragma unroll
        for (int q = 0; q < 2; ++q)
            *(f2*)(bufA + eL * SBA + h0 + 2*q) = ma[q] + mb[q];
    }
    __syncthreads();   // B1: bufA ready; ds (support) now DEAD

    // issue query-tile loads early; HBM latency hides under ph2
    float4 q0, q1;
    {
        const int n0 = tid >> 4, c0 = (tid & 15) * 4;
        q0 = *(const float4*)(d2 + (long)n0 * E_DIM + sE + c0);
        if (tid < 448) {
            const int i1 = tid + 512, n1 = i1 >> 4, c1 = (i1 & 15) * 4;
            q1 = *(const float4*)(d2 + (long)n1 * E_DIM + sE + c1);
        }
    }

    // ph2: v = relu(m @ Wgvc + bgvc) -> bufB (u_l dead)
    {
        f2 acc[2];
        #pragma unroll
        for (int q = 0; q < 2; ++q) acc[q] = f2{bgvc[h0 + 2*q], bgvc[h0 + 2*q + 1]};
        #pragma unroll
        for (int k = 0; k < H; ++k) {
            const float t = bufA[eL * SBA + k];
            const f2 t2 = f2{t, t};
            #pragma unroll
            for (int q = 0; q < 2; ++q)
                acc[q] = __builtin_elementwise_fma(t2, *(const f2*)(Wgvc + k * H + h0 + 2*q), acc[q]);
        }
        #pragma unroll
        for (int q = 0; q < 2; ++q)
            *(f2*)(bufB + eL * SBA + h0 + 2*q) = __builtin_elementwise_max(acc[q], (f2)(0.f));
    }

    // write query tile into ds (support dead since B1)
    {
        const int n0 = tid >> 4, c0 = (tid & 15) * 4;
        *(float4*)(ds + n0 * SDS + c0) = q0;
        if (tid < 448) {
            const int i1 = tid + 512, n1 = i1 >> 4, c1 = (i1 & 15) * 4;
            *(float4*)(ds + n1 * SDS + c1) = q1;
        }
    }
    __syncthreads();   // B2: bufB + query tile ready

    // ph3: vz = v @ Wz_v + b_fz -> bufT (bufA dead)
    {
        f2 acc[2];
        #pragma unroll
        for (int q = 0; q < 2; ++q) acc[q] = f2{bfz[h0 + 2*q], bfz[h0 + 2*q + 1]};
        #pragma unroll
        for (int k = 0; k < H; ++k) {
            const float t = bufB[eL * SBA + k];
            const f2 t2 = f2{t, t};
            #pragma unroll
            for (int q = 0; q < 2; ++q)
                acc[q] = __builtin_elementwise_fma(t2, *(const f2*)(Wfz + k * H + h0 + 2*q), acc[q]);
        }
        #pragma unroll
        for (int q = 0; q < 2; ++q) {
            bufT[(h0 + 2*q)     * SBT + eL] = acc[q].x;
            bufT[(h0 + 2*q + 1) * SBT + eL] = acc[q].y;
        }
    }
    __syncthreads();   // B3: bufT ready

    // ph4: z partials. wave r: n in [8r,8r+8); query rows from LDS.
    {
        const int hl = tid & 31;
        const int bn = ((tid >> 6) << 3) + ((tid >> 5) & 1) * 4;
        if (bn < N1) {
            const float wv = Wfz[H * H + hl];
            const f2 wv2 = f2{wv, wv};
            f2 acc2[4];
            #pragma unroll
            for (int i = 0; i < 4; ++i) acc2[i] = (f2)(0.f);
            const float* dr = ds + bn * SDS;
            #pragma unroll 2
            for (int e4 = 0; e4 < TEB; e4 += 4) {
                const float4 w4 = *(const float4*)(bufT + hl * SBT + e4);
                const f2 wa = f2{w4.x, w4.y}, wb = f2{w4.z, w4.w};
                #pragma unroll
                for (int i = 0; i < 4; ++i) {
                    const float4 di = *(const float4*)(dr + i * SDS + e4);
                    acc2[i] += relu_fma2(f2{di.x, di.y}, wv2, wa)
                             + relu_fma2(f2{di.z, di.w}, wv2, wb);
                }
            }
            if (ATOMIC) {
                #pragma unroll
                for (int i = 0; i < 4; ++i) atomicAdd(&outp[(bn + i) * H + hl], acc2[i].x + acc2[i].y);
            } else {
                float* base = outp + (long)blockIdx.x * PSZ;
                #pragma unroll
                for (int i = 0; i < 4; ++i) base[(bn + i) * H + hl] = acc2[i].x + acc2[i].y;
            }
        }
    }
}

// reduce part[NB2][PSZ] -> out[PSZ]; grid = PSZ/16 = 120 blocks
__global__ __launch_bounds__(256) void kR(
    const float* __restrict__ part, float* __restrict__ out)
{
    __shared__ float red[16][17];
    const int tid = threadIdx.x;
    const int oLoc = tid & 15, c = tid >> 4;
    const int o = blockIdx.x * 16 + oLoc;
    const int b0 = c * 68;
    const int bN = (NB2 - b0 < 68) ? (NB2 - b0) : 68;
    const float* p = part + (long)b0 * PSZ + o;
    float s = 0.f;
    #pragma unroll 4
    for (int b = 0; b < bN; ++b) s += p[(long)b * PSZ];
    red[c][oLoc] = s;
    __syncthreads();
    if (tid < 16) {
        float t = 0.f;
        #pragma unroll
        for (int ci = 0; ci < 16; ++ci) t += red[ci][tid];
        out[blockIdx.x * 16 + tid] = t;
    }
}

__global__ __launch_bounds__(1024) void kB(
    const float* __restrict__ alphaAcc, const int* __restrict__ label,
    const float* __restrict__ Wfvb, const float* __restrict__ bfvb,
    const float* __restrict__ Wgvb, const float* __restrict__ bgvb,
    const float* __restrict__ Wfu,  const float* __restrict__ bfu,
    const float* __restrict__ Wgu,  const float* __restrict__ bgu,
    const float* __restrict__ Wfvc, const float* __restrict__ bfvc,
    float* __restrict__ uwb)
{
    __shared__ float up_l[N1 * H];
    __shared__ float un_l[N1 * H];
    __shared__ float cb_l[CC * H];
    __shared__ float cw_l[CC * H];
    __shared__ int   cnt[CC];
    const int tid = threadIdx.x;

    if (tid < CC) cnt[tid] = 0;
    __syncthreads();
    if (tid < N1) atomicAdd(&cnt[label[tid]], 1);
    __syncthreads();

    if (tid < CC * H) {
        const int c = tid / H, h = tid % H;
        const float nc = (float)cnt[c];
        float s = bgvb[h];
        #pragma unroll
        for (int k = 0; k < H; ++k) {
            const float t1c = (nc * fmaxf(Wfvb[k] + bfvb[k], 0.f) +
                               ((float)N1 - nc) * fmaxf(bfvb[k], 0.f)) * (1.f / N1);
            s = fmaf(t1c, Wgvb[k * H + h], s);
        }
        cb_l[tid] = fmaxf(s, 0.f);
    }
    __syncthreads();
    if (tid < CC * H) {
        const int c = tid / H, h = tid % H;
        float s = bfu[h];
        #pragma unroll
        for (int k = 0; k < H; ++k) s = fmaf(cb_l[c * H + k], Wfu[k * H + h], s);
        cw_l[tid] = s;
    }
    __syncthreads();
    for (int t = tid; t < N1 * H; t += 1024) {
        const int n = t >> 5, h = t & 31;
        const int ln = label[n];
        const float wud = Wfu[H * H + h];
        float s = 0.f;
        #pragma unroll
        for (int c = 0; c < CC; ++c)
            s += fmaxf(cw_l[c * H + h] + ((c == ln) ? wud : 0.f), 0.f);
        up_l[t] = alphaAcc[t] * (1.f / E_DIM) + s * (1.f / CC);
    }
    __syncthreads();
    for (int t = tid; t < N1 * H; t += 1024) {
        const int n = t >> 5, h = t & 31;
        float s = bgu[h];
        #pragma unroll
        for (int k = 0; k < H; ++k) s = fmaf(up_l[n * H + k], Wgu[k * H + h], s);
        un_l[t] = fmaxf(s, 0.f);
    }
    __syncthreads();
    for (int t = tid; t < N1 * H; t += 1024) {
        const int n = t >> 5, h = t & 31;
        float s = bfvc[h];
        #pragma unroll
        for (int k = 0; k < H; ++k) s = fmaf(un_l[n * H + k], Wfvc[k * H + h], s);
        uwb[t] = s;
    }
}

__global__ __launch_bounds__(1024) void kD(
    const float* __restrict__ zAcc,
    const float* __restrict__ Wgz, const float* __restrict__ bgz,
    float* __restrict__ out)
{
    __shared__ float z_l[N1 * H];
    const int tid = threadIdx.x;
    for (int t = tid; t < N1 * H; t += 1024) z_l[t] = zAcc[t] * (1.f / E_DIM);
    __syncthreads();
    for (int t = tid; t < N1 * H; t += 1024) {
        const int n = t >> 5, h = t & 31;
        float s = bgz[h];
        #pragma unroll
        for (int k = 0; k < H; ++k) s = fmaf(z_l[n * H + k], Wgz[k * H + h], s);
        out[t] = fmaxf(s, 0.f);
    }
}

extern "C" void kernel_launch(void* const* d_in, const int* in_sizes, int n_in,
                              void* d_out, int out_size, void* d_ws, size_t ws_size,
                              hipStream_t stream)
{
    const float* sup  = (const float*)d_in[0];
    const int*   lab  = (const int*)d_in[1];
    const float* qry  = (const float*)d_in[2];
    const float* Wfvb = (const float*)d_in[3];
    const float* bfvb = (const float*)d_in[4];
    const float* Wgvb = (const float*)d_in[5];
    const float* bgvb = (const float*)d_in[6];
    const float* Wfu  = (const float*)d_in[7];
    const float* bfu  = (const float*)d_in[8];
    const float* Wgu  = (const float*)d_in[9];
    const float* bgu  = (const float*)d_in[10];
    const float* Wfvc = (const float*)d_in[11];
    const float* bfvc = (const float*)d_in[12];
    const float* Wgvc = (const float*)d_in[13];
    const float* bgvc = (const float*)d_in[14];
    const float* Wfz  = (const float*)d_in[15];
    const float* bfz  = (const float*)d_in[16];
    const float* Wgz  = (const float*)d_in[17];
    const float* bgz  = (const float*)d_in[18];
    float* out = (float*)d_out;

    float* alphaAcc = (float*)d_ws;
    float* zAcc     = alphaAcc + PSZ;
    float* uwb      = zAcc + PSZ;
    float* partA    = uwb + PSZ;
    float* partZ    = partA + (size_t)NB2 * PSZ;

    const size_t needMain = (3 * (size_t)PSZ + 2 * (size_t)NB2 * PSZ) * sizeof(float);

    if (ws_size >= needMain) {
        kA23<false><<<NB2, 512, 0, stream>>>(sup, Wfvb, bfvb, Wgvb, bgvb, Wfu, bfu, partA);
        kR<<<PSZ / 16, 256, 0, stream>>>(partA, alphaAcc);
        kB<<<1, 1024, 0, stream>>>(alphaAcc, lab, Wfvb, bfvb, Wgvb, bgvb, Wfu, bfu,
                                   Wgu, bgu, Wfvc, bfvc, uwb);
        kCf23<false><<<NB2, 512, 0, stream>>>(sup, qry, uwb, Wfvc, Wgvc, bgvc, Wfz, bfz, partZ);
        kR<<<PSZ / 16, 256, 0, stream>>>(partZ, zAcc);
        kD<<<1, 1024, 0, stream>>>(zAcc, Wgz, bgz, out);
    } else {
        (void)hipMemsetAsync(alphaAcc, 0, 2 * PSZ * sizeof(float), stream);
        kA23<true><<<NB2, 512, 0, stream>>>(sup, Wfvb, bfvb, Wgvb, bgvb, Wfu, bfu, alphaAcc);
        kB<<<1, 1024, 0, stream>>>(alphaAcc, lab, Wfvb, bfvb, Wgvb, bgvb, Wfu, bfu,
                                   Wgu, bgu, Wfvc, bfvc, uwb);
        kCf23<true><<<NB2, 512, 0, stream>>>(sup, qry, uwb, Wfvc, Wgvc, bgvc, Wfz, bfz, zAcc);
        kD<<<1, 1024, 0, stream>>>(zAcc, Wgz, bgz, out);
    }
}